// Round 3
// baseline (438.844 us; speedup 1.0000x reference)
//
#include <hip/hip_runtime.h>
#include <hip/hip_bf16.h>
#include <float.h>

#define K_NEI 9
#define M 4096
#define N 65536
#define D 128
#define SEGS 8                  // one segment per XCD
#define SEG_LEN (N / SEGS)      // 8192 bank rows per segment
#define QB 32                   // queries per block (2 MFMA query-tiles)
#define QT 2                    // query tiles per wave
#define RT 2                    // row tiles per wave per chunk
#define BB 128                  // bank rows per chunk (32 per wave)
#define CHUNKS (SEG_LEN / BB)   // 64
#define QGROUPS (M / QB)        // 128

typedef __bf16 bf16x8 __attribute__((ext_vector_type(8)));
typedef float floatx4 __attribute__((ext_vector_type(4)));

static __device__ inline floatx4 mfma16(bf16x8 a, bf16x8 b, floatx4 c) {
    return __builtin_amdgcn_mfma_f32_16x16x32_bf16(a, b, c, 0, 0, 0);
}

// ---- sorted-9 toolkit -----------------------------------------------------
static __device__ inline void ce(float& a, float& b) {
    float lo = fminf(a, b), hi = fmaxf(a, b); a = lo; b = hi;
}
// canonical optimal 25-CE / depth-7 sorting network for 9 (ascending)
static __device__ inline void sort9(float t[K_NEI]) {
    ce(t[0],t[3]); ce(t[1],t[7]); ce(t[2],t[5]); ce(t[4],t[8]);
    ce(t[0],t[7]); ce(t[2],t[4]); ce(t[3],t[8]); ce(t[5],t[6]);
    ce(t[0],t[2]); ce(t[1],t[3]); ce(t[4],t[5]); ce(t[7],t[8]);
    ce(t[1],t[4]); ce(t[3],t[6]); ce(t[5],t[7]);
    ce(t[0],t[1]); ce(t[2],t[4]); ce(t[3],t[5]); ce(t[6],t[8]);
    ce(t[2],t[3]); ce(t[4],t[5]); ce(t[6],t[7]);
    ce(t[1],t[2]); ce(t[3],t[4]); ce(t[5],t[6]);
}
// t, o sorted ascending -> t = sorted 9 smallest of union (bitonic min trick)
static __device__ inline void merge9(float t[K_NEI], const float o[K_NEI]) {
    float m[K_NEI];
#pragma unroll
    for (int i = 0; i < K_NEI; ++i) m[i] = fminf(t[i], o[K_NEI - 1 - i]);
    sort9(m);
#pragma unroll
    for (int i = 0; i < K_NEI; ++i) t[i] = m[i];
}
// pool the 4 partner lanes (lane ^16, ^32): all 4 end with identical exact
// top-9 of the quad's union. ONLY valid if the 4 lists are element-disjoint
// (true here: each bank row is scanned by exactly one lane).
static __device__ inline void quad_merge(float t[K_NEI]) {
    float o[K_NEI];
#pragma unroll
    for (int i = 0; i < K_NEI; ++i) o[i] = __shfl_xor(t[i], 16, 64);
    merge9(t, o);
#pragma unroll
    for (int i = 0; i < K_NEI; ++i) o[i] = __shfl_xor(t[i], 32, 64);
    merge9(t, o);
}

// ---------------------------------------------------------------------------
// Kernel 1 (fused prep): fp32 -> bf16 convert + row norms for BOTH inputs,
// plus per-call init of thr_g (gates) and done (qgroup counters).
// Round 3: 2 rows per 32-lane group (independent reduce chains -> 2x ILP;
// round-2 version measured only ~0.9 TB/s, latency-bound).
// ---------------------------------------------------------------------------
static __device__ inline unsigned pack2bf(float a, float b) {
    __hip_bfloat16 x = __float2bfloat16(a), y = __float2bfloat16(b);
    unsigned short ux = *(unsigned short*)&x, uy = *(unsigned short*)&y;
    return (unsigned)ux | ((unsigned)uy << 16);
}

__global__ void prep_kernel(const float* __restrict__ bank,
                            const float* __restrict__ feats,
                            __hip_bfloat16* __restrict__ bankbf,
                            __hip_bfloat16* __restrict__ featbf,
                            float* __restrict__ bsqn,
                            float* __restrict__ qsq,
                            int* __restrict__ thr_g,
                            int* __restrict__ done) {
    int gtid = blockIdx.x * blockDim.x + threadIdx.x;
    int row0 = (gtid >> 5) * 2;          // this 32-lane group handles row0, row0+1
    int l    = threadIdx.x & 31;
    if (row0 >= N + M) return;

    float s[2];
    float4 v[2];
#pragma unroll
    for (int rr = 0; rr < 2; ++rr) {
        int row = row0 + rr;
        const float* src = (row < N) ? (bank + (size_t)row * D)
                                     : (feats + (size_t)(row - N) * D);
        v[rr] = ((const float4*)src)[l];
        s[rr] = v[rr].x * v[rr].x + v[rr].y * v[rr].y +
                v[rr].z * v[rr].z + v[rr].w * v[rr].w;
    }
#pragma unroll
    for (int rr = 0; rr < 2; ++rr) {
        int row = row0 + rr;
        __hip_bfloat16* dst = (row < N) ? (bankbf + (size_t)row * D)
                                        : (featbf + (size_t)(row - N) * D);
        uint2 p;
        p.x = pack2bf(v[rr].x, v[rr].y);
        p.y = pack2bf(v[rr].z, v[rr].w);
        ((uint2*)dst)[l] = p;
    }
    // two independent xor-reduce chains (interleaved by the compiler)
#pragma unroll
    for (int off = 16; off > 0; off >>= 1) {
        s[0] += __shfl_xor(s[0], off, 64);
        s[1] += __shfl_xor(s[1], off, 64);
    }
    if (l == 0) {
#pragma unroll
        for (int rr = 0; rr < 2; ++rr) {
            int row = row0 + rr;
            if (row < N) {
                bsqn[row] = -0.5f * s[rr];
            } else {
                qsq[row - N] = s[rr];
                thr_g[row - N] = 0x7f7f7f7f;   // 3.39e38f
            }
        }
    }
    if (l == 1 && row0 >= N && (row0 - N) < QGROUPS) {
        done[row0 - N] = 0;
        if (row0 - N + 1 < QGROUPS) done[row0 - N + 1] = 0;
    }
}

// ---------------------------------------------------------------------------
// Kernel 2: barrier-free streaming MFMA + fused per-query top-9 + final merge.
//
// ROUND-3 CHANGES (on the round-2 barrier-free skeleton):
//  * BB 64 -> 128 (32 rows/wave/chunk, 16 MFMA/chunk): halves per-chunk
//    fixed overhead, doubles independent work covering L2 load latency.
//  * CONTINUOUS quad-min gate: a subset's 9th-smallest >= the full set's
//    9th-smallest, so min over the 4 partner lanes' g values is a VALID
//    gate bound. 2 shfl_xor + fmin per qt per chunk replaces all mid-scan
//    quad_merge events (and the leader/follower disjointness dance).
//  * Publishes: throttled atomicMin of the quad-min every 4th chunk, only
//    on >0.2% improvement. Refresh: issue (ch&3)==0, consume (ch&3)==2.
//
// acc init = -0.5*bs (fp32, via MFMA C-input) => acc = dot - 0.5*bs =>
// d2 = qs - 2*acc. Gate: d2 <= g  <=>  acc >= h = 0.5*(qs - g).
// Exactness is gate-independent: skipped elements satisfy d2 > g >= true
// 9th, so every true top-9 element is inserted by its owning lane.
// Epilogue: quad pool (element-disjoint lists) -> cross-wave pool via LDS ->
// part write; last seg-block per qgroup (done counter + fence + agent-scope
// loads) folds the 8 sorted per-seg lists and writes the output.
// ---------------------------------------------------------------------------
__global__ __launch_bounds__(256, 3)
void knn_main(const __hip_bfloat16* __restrict__ bankbf,
              const __hip_bfloat16* __restrict__ featbf,
              const float* __restrict__ bsqn,
              const float* __restrict__ qsqp,
              int* __restrict__ thr_g,
              float* __restrict__ part,
              int* __restrict__ done,
              float* __restrict__ out) {
    __shared__ __align__(16) float sm_pool[4][QB][K_NEI];  // 4.6 KB
    __shared__ int sm_last;

    const int tid  = threadIdx.x;
    const int lane = tid & 63;
    const int wv   = tid >> 6;
    const int l15  = lane & 15, l4 = lane >> 4;

    const int seg   = blockIdx.x & 7;     // == XCD id (L2-resident segment)
    const int bq    = blockIdx.x >> 3;    // 0..127
    const int qbase = bq * QB;
    const int sbase = seg * SEG_LEN;

    // query fragments (B operand) in registers for the whole kernel
    bf16x8 qf[QT][4];
    float qs[QT], g[QT], lastpub[QT];
    float t9[QT][K_NEI];
#pragma unroll
    for (int qt = 0; qt < QT; ++qt) {
        int q = qbase + qt * 16 + l15;
        qs[qt] = qsqp[q];
        g[qt]  = FLT_MAX;
        lastpub[qt] = FLT_MAX;
#pragma unroll
        for (int ks = 0; ks < 4; ++ks)
            qf[qt][ks] = *(const bf16x8*)(featbf + (size_t)q * D + ks * 32 + l4 * 8);
#pragma unroll
        for (int j = 0; j < K_NEI; ++j) t9[qt][j] = FLT_MAX;
    }

    // per-wave bank bases: row = sbase + wv*32 + rt*16 + l15, k-slice l4*8
    const __hip_bfloat16* ab[RT];
#pragma unroll
    for (int rt = 0; rt < RT; ++rt)
        ab[rt] = bankbf + (size_t)(sbase + wv * 32 + rt * 16 + l15) * D + l4 * 8;
    const float* ibq = bsqn + sbase + wv * 32 + l4 * 4;   // + rt*16 + ch*BB

    // prologue: chunk 0 fragments + acc-init
    bf16x8 af[RT][4];
    floatx4 ini[RT];
#pragma unroll
    for (int rt = 0; rt < RT; ++rt) {
#pragma unroll
        for (int ks = 0; ks < 4; ++ks)
            af[rt][ks] = *(const bf16x8*)(ab[rt] + ks * 32);
        ini[rt] = *(const floatx4*)(ibq + rt * 16);
    }

    int tg0 = 0x7f7f7f7f, tg1 = 0x7f7f7f7f;

#pragma unroll 1
    for (int ch = 0; ch < CHUNKS; ++ch) {
        // ---- MFMA on current chunk (af/ini loaded last iteration) ----
        floatx4 acc[RT][QT];
#pragma unroll
        for (int rt = 0; rt < RT; ++rt)
#pragma unroll
            for (int qt = 0; qt < QT; ++qt)
                acc[rt][qt] = mfma16(af[rt][0], qf[qt][0], ini[rt]);
#pragma unroll
        for (int ks = 1; ks < 4; ++ks)
#pragma unroll
            for (int rt = 0; rt < RT; ++rt)
#pragma unroll
                for (int qt = 0; qt < QT; ++qt)
                    acc[rt][qt] = mfma16(af[rt][ks], qf[qt][ks], acc[rt][qt]);

        // ---- issue next chunk's loads; latency hides under selection ----
        if (ch + 1 < CHUNKS) {
            const size_t coff = (size_t)(ch + 1) * (BB * D);
#pragma unroll
            for (int rt = 0; rt < RT; ++rt) {
#pragma unroll
                for (int ks = 0; ks < 4; ++ks)
                    af[rt][ks] = *(const bf16x8*)(ab[rt] + coff + ks * 32);
                ini[rt] = *(const floatx4*)(ibq + (ch + 1) * BB + rt * 16);
            }
        }

        // ---- gate refresh: issue every 4th chunk, consume 2 chunks later ----
        if ((ch & 3) == 0) {
            tg0 = __hip_atomic_load(&thr_g[qbase + l15], __ATOMIC_RELAXED,
                                    __HIP_MEMORY_SCOPE_AGENT);
            tg1 = __hip_atomic_load(&thr_g[qbase + 16 + l15], __ATOMIC_RELAXED,
                                    __HIP_MEMORY_SCOPE_AGENT);
        } else if ((ch & 3) == 2) {
            g[0] = fminf(g[0], __int_as_float(tg0));
            g[1] = fminf(g[1], __int_as_float(tg1));
        }
        float h[QT];
#pragma unroll
        for (int qt = 0; qt < QT; ++qt)
            h[qt] = 0.5f * (qs[qt] - g[qt] * 1.0000005f);

        // ---- selection: 1 reg-max + 1 v_cmp per 4 elements; rare inserts ----
#pragma unroll
        for (int rt = 0; rt < RT; ++rt) {
#pragma unroll
            for (int qt = 0; qt < QT; ++qt) {
                float a0 = acc[rt][qt][0], a1 = acc[rt][qt][1];
                float a2 = acc[rt][qt][2], a3 = acc[rt][qt][3];
                float mx = fmaxf(fmaxf(a0, a1), fmaxf(a2, a3));
                if (__ballot(mx >= h[qt])) {
#pragma unroll
                    for (int r = 0; r < 4; ++r) {
                        float a = acc[rt][qt][r];
                        if (a >= h[qt]) {
                            float d2 = fmaxf(fmaf(-2.f, a, qs[qt]), 0.f);
                            if (d2 <= g[qt]) {
                                t9[qt][K_NEI - 1] = d2;
#pragma unroll
                                for (int s = K_NEI - 1; s > 0; --s)
                                    ce(t9[qt][s - 1], t9[qt][s]);
                                g[qt] = fminf(g[qt], t9[qt][K_NEI - 1]);
                            }
                        }
                    }
                }
            }
        }

        // ---- continuous quad-min gate (subset-9th >= global-9th => valid) ----
#pragma unroll
        for (int qt = 0; qt < QT; ++qt) {
            float gq = fminf(g[qt], __shfl_xor(g[qt], 16, 64));
            gq = fminf(gq, __shfl_xor(gq, 32, 64));
            g[qt] = gq;
        }
        // ---- throttled publish every 4th chunk, only on >0.2% improvement ----
        if ((ch & 3) == 3) {
#pragma unroll
            for (int qt = 0; qt < QT; ++qt) {
                if (g[qt] < lastpub[qt] * 0.998f) {
                    if (l4 == 0)
                        atomicMin(&thr_g[qbase + qt * 16 + l15],
                                  __float_as_int(g[qt]));
                    lastpub[qt] = g[qt];
                }
            }
        }
    }

    // ---- epilogue: quad pool (disjoint), then 4-wave pool via LDS ---------
#pragma unroll
    for (int qt = 0; qt < QT; ++qt) quad_merge(t9[qt]);
    if (l4 == 0) {
#pragma unroll
        for (int qt = 0; qt < QT; ++qt)
#pragma unroll
            for (int j = 0; j < K_NEI; ++j)
                sm_pool[wv][qt * 16 + l15][j] = t9[qt][j];
    }
    __syncthreads();
    if (tid < QB) {
        float R[K_NEI];
#pragma unroll
        for (int j = 0; j < K_NEI; ++j) R[j] = sm_pool[0][tid][j];
#pragma unroll
        for (int w = 1; w < 4; ++w) {
            float o[K_NEI];
#pragma unroll
            for (int j = 0; j < K_NEI; ++j) o[j] = sm_pool[w][tid][j];
            merge9(R, o);
        }
        float* dst = part + ((size_t)(qbase + tid) * SEGS + seg) * K_NEI;
#pragma unroll
        for (int j = 0; j < K_NEI; ++j) dst[j] = R[j];
    }

    // ---- fused final: last seg-block of this qgroup folds 8 sorted lists --
    __threadfence();            // release our part writes device-wide
    __syncthreads();
    if (tid == 0)
        sm_last = (atomicAdd(&done[bq], 1) == SEGS - 1) ? 1 : 0;
    __syncthreads();
    if (sm_last && tid < QB) {
        int q = qbase + tid;
        const float* p = part + (size_t)q * SEGS * K_NEI;
        float R[K_NEI], nx[K_NEI];
#pragma unroll
        for (int j = 0; j < K_NEI; ++j)
            R[j] = __hip_atomic_load(p + j, __ATOMIC_RELAXED,
                                     __HIP_MEMORY_SCOPE_AGENT);
#pragma unroll
        for (int j = 0; j < K_NEI; ++j)
            nx[j] = __hip_atomic_load(p + K_NEI + j, __ATOMIC_RELAXED,
                                      __HIP_MEMORY_SCOPE_AGENT);
#pragma unroll 1
        for (int s = 1; s < SEGS; ++s) {
            float o[K_NEI];
#pragma unroll
            for (int j = 0; j < K_NEI; ++j) o[j] = nx[j];
            if (s + 1 < SEGS) {
#pragma unroll
                for (int j = 0; j < K_NEI; ++j)
                    nx[j] = __hip_atomic_load(p + (s + 1) * K_NEI + j,
                                              __ATOMIC_RELAXED,
                                              __HIP_MEMORY_SCOPE_AGENT);
            }
            merge9(R, o);
        }
        float sum = 0.f;
#pragma unroll
        for (int j = 0; j < K_NEI; ++j) sum += sqrtf(fmaxf(R[j], 0.f));
        out[q] = sum * (1.0f / 9.0f);
    }
}

// ---------------------------------------------------------------------------
extern "C" void kernel_launch(void* const* d_in, const int* in_sizes, int n_in,
                              void* d_out, int out_size, void* d_ws, size_t ws_size,
                              hipStream_t stream) {
    const float* feats = (const float*)d_in[0];   // [M, D]
    const float* bank  = (const float*)d_in[1];   // [N, D]

    char* w = (char*)d_ws;
    __hip_bfloat16* bankbf = (__hip_bfloat16*)w;                       // 16 MB
    __hip_bfloat16* featbf = (__hip_bfloat16*)(w + (size_t)N * D * 2); // 1 MB
    float* bsqn = (float*)(w + (size_t)(N + M) * D * 2);               // 256 KB
    float* qsqp = bsqn + N;                                            // 16 KB
    float* part = qsqp + M;                                            // 1.2 MB
    int*   thr_g = (int*)(part + (size_t)M * SEGS * K_NEI);            // 16 KB
    int*   done  = thr_g + M;                                          // 512 B
    float* out  = (float*)d_out;

    prep_kernel<<<(N + M) / 16, 256, 0, stream>>>(bank, feats, bankbf, featbf,
                                                  bsqn, qsqp, thr_g, done);
    knn_main<<<QGROUPS * SEGS, 256, 0, stream>>>(bankbf, featbf, bsqn, qsqp,
                                                 thr_g, part, done, out);
}

// Round 4
// 421.392 us; speedup vs baseline: 1.0414x; 1.0414x over previous
//
#include <hip/hip_runtime.h>
#include <hip/hip_bf16.h>
#include <float.h>

#define K_NEI 9
#define M 4096
#define N 65536
#define D 128
#define SEGS 8                  // one segment per XCD
#define SEG_LEN (N / SEGS)      // 8192 bank rows per segment
#define QB 64                   // queries per block (4 MFMA query-tiles)
#define QT 4                    // query tiles per wave
#define RT 2                    // row tiles per wave per chunk
#define BB 128                  // bank rows per chunk (32 per wave)
#define CHUNKS (SEG_LEN / BB)   // 64
#define QGROUPS (M / QB)        // 64
#define GUARD 1.0000005f

typedef __bf16 bf16x8 __attribute__((ext_vector_type(8)));
typedef float floatx4 __attribute__((ext_vector_type(4)));

static __device__ inline floatx4 mfma16(bf16x8 a, bf16x8 b, floatx4 c) {
    return __builtin_amdgcn_mfma_f32_16x16x32_bf16(a, b, c, 0, 0, 0);
}

// ---- sorted-9 toolkit -----------------------------------------------------
static __device__ inline void ce(float& a, float& b) {
    float lo = fminf(a, b), hi = fmaxf(a, b); a = lo; b = hi;
}
static __device__ inline void sort9(float t[K_NEI]) {
    ce(t[0],t[3]); ce(t[1],t[7]); ce(t[2],t[5]); ce(t[4],t[8]);
    ce(t[0],t[7]); ce(t[2],t[4]); ce(t[3],t[8]); ce(t[5],t[6]);
    ce(t[0],t[2]); ce(t[1],t[3]); ce(t[4],t[5]); ce(t[7],t[8]);
    ce(t[1],t[4]); ce(t[3],t[6]); ce(t[5],t[7]);
    ce(t[0],t[1]); ce(t[2],t[4]); ce(t[3],t[5]); ce(t[6],t[8]);
    ce(t[2],t[3]); ce(t[4],t[5]); ce(t[6],t[7]);
    ce(t[1],t[2]); ce(t[3],t[4]); ce(t[5],t[6]);
}
static __device__ inline void merge9(float t[K_NEI], const float o[K_NEI]) {
    float m[K_NEI];
#pragma unroll
    for (int i = 0; i < K_NEI; ++i) m[i] = fminf(t[i], o[K_NEI - 1 - i]);
    sort9(m);
#pragma unroll
    for (int i = 0; i < K_NEI; ++i) t[i] = m[i];
}
// pool the 4 partner lanes (lane ^16, ^32). Valid only for element-disjoint
// lists (true: each bank row / stream belongs to exactly one lane).
static __device__ inline void quad_merge(float t[K_NEI]) {
    float o[K_NEI];
#pragma unroll
    for (int i = 0; i < K_NEI; ++i) o[i] = __shfl_xor(t[i], 16, 64);
    merge9(t, o);
#pragma unroll
    for (int i = 0; i < K_NEI; ++i) o[i] = __shfl_xor(t[i], 32, 64);
    merge9(t, o);
}
static __device__ inline float wave_max(float x) {
#pragma unroll
    for (int off = 1; off < 64; off <<= 1) x = fmaxf(x, __shfl_xor(x, off, 64));
    return x;
}

// ---------------------------------------------------------------------------
// Kernel 1 (fused prep): fp32 -> bf16 + row norms + thr_g/done init.
// ---------------------------------------------------------------------------
static __device__ inline unsigned pack2bf(float a, float b) {
    __hip_bfloat16 x = __float2bfloat16(a), y = __float2bfloat16(b);
    unsigned short ux = *(unsigned short*)&x, uy = *(unsigned short*)&y;
    return (unsigned)ux | ((unsigned)uy << 16);
}

__global__ void prep_kernel(const float* __restrict__ bank,
                            const float* __restrict__ feats,
                            __hip_bfloat16* __restrict__ bankbf,
                            __hip_bfloat16* __restrict__ featbf,
                            float* __restrict__ bsqn,
                            float* __restrict__ qsq,
                            int* __restrict__ thr_g,
                            int* __restrict__ done) {
    int gtid = blockIdx.x * blockDim.x + threadIdx.x;
    int row0 = (gtid >> 5) * 2;
    int l    = threadIdx.x & 31;
    if (row0 >= N + M) return;

    float s[2];
    float4 v[2];
#pragma unroll
    for (int rr = 0; rr < 2; ++rr) {
        int row = row0 + rr;
        const float* src = (row < N) ? (bank + (size_t)row * D)
                                     : (feats + (size_t)(row - N) * D);
        v[rr] = ((const float4*)src)[l];
        s[rr] = v[rr].x * v[rr].x + v[rr].y * v[rr].y +
                v[rr].z * v[rr].z + v[rr].w * v[rr].w;
    }
#pragma unroll
    for (int rr = 0; rr < 2; ++rr) {
        int row = row0 + rr;
        __hip_bfloat16* dst = (row < N) ? (bankbf + (size_t)row * D)
                                        : (featbf + (size_t)(row - N) * D);
        uint2 p;
        p.x = pack2bf(v[rr].x, v[rr].y);
        p.y = pack2bf(v[rr].z, v[rr].w);
        ((uint2*)dst)[l] = p;
    }
#pragma unroll
    for (int off = 16; off > 0; off >>= 1) {
        s[0] += __shfl_xor(s[0], off, 64);
        s[1] += __shfl_xor(s[1], off, 64);
    }
    if (l == 0) {
#pragma unroll
        for (int rr = 0; rr < 2; ++rr) {
            int row = row0 + rr;
            if (row < N) {
                bsqn[row] = -0.5f * s[rr];
            } else {
                qsq[row - N] = s[rr];
                thr_g[row - N] = 0x7f7f7f7f;   // 3.39e38f
            }
        }
    }
    if (l == 1 && row0 >= N && (row0 - N) < QGROUPS) {
        done[row0 - N] = 0;
        if (row0 - N + 1 < QGROUPS) done[row0 - N + 1] = 0;
    }
}

// ---------------------------------------------------------------------------
// Kernel 2 (ROUND-4 two-pass redesign, barrier-free streaming skeleton):
//
// PASS 1 (branchless, MFMA-bound): full scan of the block's 8192-row slice.
// Per (lane,qt,reg) track stream maxima of acc (16 disjoint streams per quad
// per query -> 9th-smallest of the 16 stream-min-d2s is a VALID upper bound
// on the true 9th distance). Per tile compute tk = max over 256 values of
// (2*acc - qs) = -(min d2 in tile), wave-reduced, stored in this wave's
// PRIVATE LDS flag array (written & read by the same wave -> no barrier).
// No ballots, no inserts: this kills the insert-flood that capped r0-r3.
//
// PASS 2 (sparse, exact): gate g = min(own bound, cross-wave LDS pool,
// cross-block thr_g). Re-walk all chunks; skip any tile with
// tk < -gmax*GUARD  (provably contains no value with d2 <= any lane's gate
// >= true 9th -> distance-exact). Fired tiles redo the MFMA (identical
// inputs -> bit-identical acc, so flags are exact) + r3 ballot/insert.
// Gate refresh from thr_g every 16 chunks (stale = looser = safe).
//
// Epilogue: quad pool -> cross-wave pool via LDS -> part write; last
// seg-block per qgroup folds the 8 sorted per-seg lists (unchanged).
// grid = 512 blocks (exactly 2/CU, no tail) of 256 threads; seg==blockIdx&7
// keeps each XCD's 2 MB segment L2-resident across both passes.
// ---------------------------------------------------------------------------
__global__ __launch_bounds__(256, 2)
void knn_main(const __hip_bfloat16* __restrict__ bankbf,
              const __hip_bfloat16* __restrict__ featbf,
              const float* __restrict__ bsqn,
              const float* __restrict__ qsqp,
              int* __restrict__ thr_g,
              float* __restrict__ part,
              int* __restrict__ done,
              float* __restrict__ out) {
    __shared__ __align__(16) float tk_lds[4][CHUNKS][RT][QT];  // 8 KB, wave-private
    __shared__ __align__(16) float sm_g[4][QB];                // 1 KB bound pool
    __shared__ __align__(16) float sm_pool[4][QB][K_NEI];      // 9 KB epilogue
    __shared__ int sm_last;

    const int tid  = threadIdx.x;
    const int lane = tid & 63;
    const int wv   = tid >> 6;
    const int l15  = lane & 15, l4 = lane >> 4;

    const int seg   = blockIdx.x & 7;     // == XCD id (L2-resident segment)
    const int bq    = blockIdx.x >> 3;    // 0..63
    const int qbase = bq * QB;
    const int sbase = seg * SEG_LEN;

    // init own bound-pool slice; one-time barrier orders init vs later reads
    sm_g[wv][lane] = FLT_MAX;
    __syncthreads();

    // query fragments (B operand) in registers for the whole kernel
    bf16x8 qf[QT][4];
    float qs[QT];
#pragma unroll
    for (int qt = 0; qt < QT; ++qt) {
        int q = qbase + qt * 16 + l15;
        qs[qt] = qsqp[q];
#pragma unroll
        for (int ks = 0; ks < 4; ++ks)
            qf[qt][ks] = *(const bf16x8*)(featbf + (size_t)q * D + ks * 32 + l4 * 8);
    }

    // per-wave bank bases: row = sbase + wv*32 + rt*16 + l15, k-slice l4*8
    const __hip_bfloat16* ab[RT];
#pragma unroll
    for (int rt = 0; rt < RT; ++rt)
        ab[rt] = bankbf + (size_t)(sbase + wv * 32 + rt * 16 + l15) * D + l4 * 8;
    const float* ibq = bsqn + sbase + wv * 32 + l4 * 4;   // + rt*16 + ch*BB

    bf16x8 af[RT][4];
    floatx4 ini[RT];
    // prologue: chunk-0 fragments + acc-init
#pragma unroll
    for (int rt = 0; rt < RT; ++rt) {
#pragma unroll
        for (int ks = 0; ks < 4; ++ks)
            af[rt][ks] = *(const bf16x8*)(ab[rt] + ks * 32);
        ini[rt] = *(const floatx4*)(ibq + rt * 16);
    }

    // ======================= PASS 1: branchless scan =======================
    floatx4 amax[QT];
#pragma unroll
    for (int qt = 0; qt < QT; ++qt)
#pragma unroll
        for (int r = 0; r < 4; ++r) amax[qt][r] = -FLT_MAX;

#pragma unroll 1
    for (int ci = 0; ci < CHUNKS; ++ci) {
        floatx4 acc[RT][QT];
#pragma unroll
        for (int rt = 0; rt < RT; ++rt)
#pragma unroll
            for (int qt = 0; qt < QT; ++qt)
                acc[rt][qt] = mfma16(af[rt][0], qf[qt][0], ini[rt]);
#pragma unroll
        for (int ks = 1; ks < 4; ++ks)
#pragma unroll
            for (int rt = 0; rt < RT; ++rt)
#pragma unroll
                for (int qt = 0; qt < QT; ++qt)
                    acc[rt][qt] = mfma16(af[rt][ks], qf[qt][ks], acc[rt][qt]);

        if (ci + 1 < CHUNKS) {
            const size_t coff = (size_t)(ci + 1) * (BB * D);
#pragma unroll
            for (int rt = 0; rt < RT; ++rt) {
#pragma unroll
                for (int ks = 0; ks < 4; ++ks)
                    af[rt][ks] = *(const bf16x8*)(ab[rt] + coff + ks * 32);
                ini[rt] = *(const floatx4*)(ibq + (ci + 1) * BB + rt * 16);
            }
        }

        // stream maxima + per-tile keys (no branches, no inserts)
#pragma unroll
        for (int rt = 0; rt < RT; ++rt) {
#pragma unroll
            for (int qt = 0; qt < QT; ++qt) {
                float k = fmaf(2.f, acc[rt][qt][0], -qs[qt]);
                k = fmaxf(k, fmaf(2.f, acc[rt][qt][1], -qs[qt]));
                k = fmaxf(k, fmaf(2.f, acc[rt][qt][2], -qs[qt]));
                k = fmaxf(k, fmaf(2.f, acc[rt][qt][3], -qs[qt]));
#pragma unroll
                for (int r = 0; r < 4; ++r)
                    amax[qt][r] = fmaxf(amax[qt][r], acc[rt][qt][r]);
                float tk = wave_max(k);            // -(min d2 of this tile)
                if (lane == 0) tk_lds[wv][ci][rt][qt] = tk;
            }
        }
    }

    // ---- bound: 9th smallest of the quad's 16 disjoint-stream minima ------
    float g[QT];
#pragma unroll
    for (int qt = 0; qt < QT; ++qt) {
        float tb[K_NEI];
#pragma unroll
        for (int r = 0; r < 4; ++r)
            tb[r] = fmaxf(fmaf(-2.f, amax[qt][r], qs[qt]), 0.f);
#pragma unroll
        for (int r = 4; r < K_NEI; ++r) tb[r] = FLT_MAX;
        sort9(tb);
        quad_merge(tb);            // 16 disjoint stream minima pooled
        float bound = tb[K_NEI - 1];
        if (l4 == 0)
            atomicMin(&thr_g[qbase + qt * 16 + l15], __float_as_int(bound));
        sm_g[wv][qt * 16 + l15] = bound;   // quad lanes write same value
        g[qt] = bound;
    }
    // cross-wave pool (benign race: unwritten slots are FLT_MAX = looser)
#pragma unroll
    for (int qt = 0; qt < QT; ++qt) {
        float m0 = fminf(fminf(sm_g[0][qt * 16 + l15], sm_g[1][qt * 16 + l15]),
                         fminf(sm_g[2][qt * 16 + l15], sm_g[3][qt * 16 + l15]));
        g[qt] = fminf(g[qt], m0);
    }
    // cross-block bounds (blocks finish pass 1 near-simultaneously)
    int tg[QT];
#pragma unroll
    for (int qt = 0; qt < QT; ++qt)
        tg[qt] = __hip_atomic_load(&thr_g[qbase + qt * 16 + l15],
                                   __ATOMIC_RELAXED, __HIP_MEMORY_SCOPE_AGENT);
#pragma unroll
    for (int qt = 0; qt < QT; ++qt)
        g[qt] = fminf(g[qt], __int_as_float(tg[qt]));

    float t9[QT][K_NEI];
#pragma unroll
    for (int qt = 0; qt < QT; ++qt)
#pragma unroll
        for (int j = 0; j < K_NEI; ++j) t9[qt][j] = FLT_MAX;

    float h[QT], fthr[QT];
#define RECOMP_GATES()                                                       \
    _Pragma("unroll")                                                        \
    for (int qt = 0; qt < QT; ++qt) {                                        \
        h[qt] = 0.5f * (qs[qt] - g[qt] * GUARD);                             \
        float gm = wave_max(g[qt]);                                          \
        fthr[qt] = -gm * GUARD;                                              \
    }
    RECOMP_GATES();

    // ======================= PASS 2: sparse exact pass =====================
    int frt[RT], ftl[RT][QT];
#pragma unroll
    for (int rt = 0; rt < RT; ++rt) {
        frt[rt] = 0;
#pragma unroll
        for (int qt = 0; qt < QT; ++qt) {
            float tk = tk_lds[wv][0][rt][qt];
            ftl[rt][qt] = (tk >= fthr[qt]);
            frt[rt] |= ftl[rt][qt];
        }
    }
#pragma unroll
    for (int rt = 0; rt < RT; ++rt) {
        if (frt[rt]) {
#pragma unroll
            for (int ks = 0; ks < 4; ++ks)
                af[rt][ks] = *(const bf16x8*)(ab[rt] + ks * 32);
        }
        ini[rt] = *(const floatx4*)(ibq + rt * 16);
    }

#pragma unroll 1
    for (int ci = 0; ci < CHUNKS; ++ci) {
        // MFMA only on fired tiles (flags exact: identical recompute)
        floatx4 acc[RT][QT];
#pragma unroll
        for (int rt = 0; rt < RT; ++rt) {
            if (frt[rt]) {
#pragma unroll
                for (int qt = 0; qt < QT; ++qt) {
                    if (ftl[rt][qt]) {
                        floatx4 a = mfma16(af[rt][0], qf[qt][0], ini[rt]);
                        a = mfma16(af[rt][1], qf[qt][1], a);
                        a = mfma16(af[rt][2], qf[qt][2], a);
                        a = mfma16(af[rt][3], qf[qt][3], a);
                        acc[rt][qt] = a;
                    }
                }
            }
        }

        // prefetch next chunk's flags + conditional fragment loads
        int nfrt[RT], nftl[RT][QT];
        if (ci + 1 < CHUNKS) {
#pragma unroll
            for (int rt = 0; rt < RT; ++rt) {
                nfrt[rt] = 0;
#pragma unroll
                for (int qt = 0; qt < QT; ++qt) {
                    float tk = tk_lds[wv][ci + 1][rt][qt];
                    nftl[rt][qt] = (tk >= fthr[qt]);
                    nfrt[rt] |= nftl[rt][qt];
                }
            }
            const size_t coff = (size_t)(ci + 1) * (BB * D);
#pragma unroll
            for (int rt = 0; rt < RT; ++rt) {
                if (nfrt[rt]) {
#pragma unroll
                    for (int ks = 0; ks < 4; ++ks)
                        af[rt][ks] = *(const bf16x8*)(ab[rt] + coff + ks * 32);
                }
                ini[rt] = *(const floatx4*)(ibq + (ci + 1) * BB + rt * 16);
            }
        }

        // selection on fired tiles (r3 ballot/insert; exactness per-lane)
#pragma unroll
        for (int rt = 0; rt < RT; ++rt) {
            if (frt[rt]) {
#pragma unroll
                for (int qt = 0; qt < QT; ++qt) {
                    if (ftl[rt][qt]) {
                        float a0 = acc[rt][qt][0], a1 = acc[rt][qt][1];
                        float a2 = acc[rt][qt][2], a3 = acc[rt][qt][3];
                        float mx = fmaxf(fmaxf(a0, a1), fmaxf(a2, a3));
                        if (__ballot(mx >= h[qt])) {
#pragma unroll
                            for (int r = 0; r < 4; ++r) {
                                float a = acc[rt][qt][r];
                                if (a >= h[qt]) {
                                    float d2 = fmaxf(fmaf(-2.f, a, qs[qt]), 0.f);
                                    if (d2 <= g[qt]) {
                                        t9[qt][K_NEI - 1] = d2;
#pragma unroll
                                        for (int s = K_NEI - 1; s > 0; --s)
                                            ce(t9[qt][s - 1], t9[qt][s]);
                                        g[qt] = fminf(g[qt], t9[qt][K_NEI - 1]);
                                    }
                                }
                            }
                        }
                    }
                }
            }
        }
#pragma unroll
        for (int rt = 0; rt < RT; ++rt) {
            frt[rt] = nfrt[rt];
#pragma unroll
            for (int qt = 0; qt < QT; ++qt) ftl[rt][qt] = nftl[rt][qt];
        }

        // periodic cross-block gate refresh (stale = looser = safe)
        if ((ci & 15) == 4) {
#pragma unroll
            for (int qt = 0; qt < QT; ++qt)
                tg[qt] = __hip_atomic_load(&thr_g[qbase + qt * 16 + l15],
                                           __ATOMIC_RELAXED,
                                           __HIP_MEMORY_SCOPE_AGENT);
        } else if ((ci & 15) == 6) {
#pragma unroll
            for (int qt = 0; qt < QT; ++qt)
                g[qt] = fminf(g[qt], __int_as_float(tg[qt]));
            RECOMP_GATES();
        }
    }

    // ---- epilogue: quad pool (disjoint), then 4-wave pool via LDS ---------
#pragma unroll
    for (int qt = 0; qt < QT; ++qt) quad_merge(t9[qt]);
    if (l4 == 0) {
#pragma unroll
        for (int qt = 0; qt < QT; ++qt)
#pragma unroll
            for (int j = 0; j < K_NEI; ++j)
                sm_pool[wv][qt * 16 + l15][j] = t9[qt][j];
    }
    __syncthreads();
    if (tid < QB) {
        float R[K_NEI];
#pragma unroll
        for (int j = 0; j < K_NEI; ++j) R[j] = sm_pool[0][tid][j];
#pragma unroll
        for (int w = 1; w < 4; ++w) {
            float o[K_NEI];
#pragma unroll
            for (int j = 0; j < K_NEI; ++j) o[j] = sm_pool[w][tid][j];
            merge9(R, o);
        }
        float* dst = part + ((size_t)(qbase + tid) * SEGS + seg) * K_NEI;
#pragma unroll
        for (int j = 0; j < K_NEI; ++j) dst[j] = R[j];
    }

    // ---- fused final: last seg-block of this qgroup folds 8 sorted lists --
    __threadfence();
    __syncthreads();
    if (tid == 0)
        sm_last = (atomicAdd(&done[bq], 1) == SEGS - 1) ? 1 : 0;
    __syncthreads();
    if (sm_last && tid < QB) {
        int q = qbase + tid;
        const float* p = part + (size_t)q * SEGS * K_NEI;
        float R[K_NEI], nx[K_NEI];
#pragma unroll
        for (int j = 0; j < K_NEI; ++j)
            R[j] = __hip_atomic_load(p + j, __ATOMIC_RELAXED,
                                     __HIP_MEMORY_SCOPE_AGENT);
#pragma unroll
        for (int j = 0; j < K_NEI; ++j)
            nx[j] = __hip_atomic_load(p + K_NEI + j, __ATOMIC_RELAXED,
                                      __HIP_MEMORY_SCOPE_AGENT);
#pragma unroll 1
        for (int s = 1; s < SEGS; ++s) {
            float o[K_NEI];
#pragma unroll
            for (int j = 0; j < K_NEI; ++j) o[j] = nx[j];
            if (s + 1 < SEGS) {
#pragma unroll
                for (int j = 0; j < K_NEI; ++j)
                    nx[j] = __hip_atomic_load(p + (s + 1) * K_NEI + j,
                                              __ATOMIC_RELAXED,
                                              __HIP_MEMORY_SCOPE_AGENT);
            }
            merge9(R, o);
        }
        float sum = 0.f;
#pragma unroll
        for (int j = 0; j < K_NEI; ++j) sum += sqrtf(fmaxf(R[j], 0.f));
        out[q] = sum * (1.0f / 9.0f);
    }
}

// ---------------------------------------------------------------------------
extern "C" void kernel_launch(void* const* d_in, const int* in_sizes, int n_in,
                              void* d_out, int out_size, void* d_ws, size_t ws_size,
                              hipStream_t stream) {
    const float* feats = (const float*)d_in[0];   // [M, D]
    const float* bank  = (const float*)d_in[1];   // [N, D]

    char* w = (char*)d_ws;
    __hip_bfloat16* bankbf = (__hip_bfloat16*)w;                       // 16 MB
    __hip_bfloat16* featbf = (__hip_bfloat16*)(w + (size_t)N * D * 2); // 1 MB
    float* bsqn = (float*)(w + (size_t)(N + M) * D * 2);               // 256 KB
    float* qsqp = bsqn + N;                                            // 16 KB
    float* part = qsqp + M;                                            // 1.2 MB
    int*   thr_g = (int*)(part + (size_t)M * SEGS * K_NEI);            // 16 KB
    int*   done  = thr_g + M;                                          // 256 B
    float* out  = (float*)d_out;

    prep_kernel<<<(N + M) / 16, 256, 0, stream>>>(bank, feats, bankbf, featbf,
                                                  bsqn, qsqp, thr_g, done);
    knn_main<<<QGROUPS * SEGS, 256, 0, stream>>>(bankbf, featbf, bsqn, qsqp,
                                                 thr_g, part, done, out);
}

// Round 5
// 420.599 us; speedup vs baseline: 1.0434x; 1.0019x over previous
//
#include <hip/hip_runtime.h>
#include <hip/hip_bf16.h>
#include <float.h>

#define K_NEI 9
#define M 4096
#define N 65536
#define D 128
#define SEGS 8                  // one segment per XCD
#define SEG_LEN (N / SEGS)      // 8192 bank rows per segment
#define QB 64                   // queries per block (4 MFMA query-tiles)
#define QT 4                    // query tiles per wave
#define RT 2                    // row tiles per wave per chunk
#define BB 128                  // bank rows per chunk (32 per wave)
#define CHUNKS (SEG_LEN / BB)   // 64
#define QGROUPS (M / QB)        // 64
#define GUARD 1.0000005f

typedef __bf16 bf16x8 __attribute__((ext_vector_type(8)));
typedef float floatx4 __attribute__((ext_vector_type(4)));

static __device__ inline floatx4 mfma16(bf16x8 a, bf16x8 b, floatx4 c) {
    return __builtin_amdgcn_mfma_f32_16x16x32_bf16(a, b, c, 0, 0, 0);
}

// ---- sorted-9 toolkit -----------------------------------------------------
static __device__ inline void ce(float& a, float& b) {
    float lo = fminf(a, b), hi = fmaxf(a, b); a = lo; b = hi;
}
static __device__ inline void sort9(float t[K_NEI]) {
    ce(t[0],t[3]); ce(t[1],t[7]); ce(t[2],t[5]); ce(t[4],t[8]);
    ce(t[0],t[7]); ce(t[2],t[4]); ce(t[3],t[8]); ce(t[5],t[6]);
    ce(t[0],t[2]); ce(t[1],t[3]); ce(t[4],t[5]); ce(t[7],t[8]);
    ce(t[1],t[4]); ce(t[3],t[6]); ce(t[5],t[7]);
    ce(t[0],t[1]); ce(t[2],t[4]); ce(t[3],t[5]); ce(t[6],t[8]);
    ce(t[2],t[3]); ce(t[4],t[5]); ce(t[6],t[7]);
    ce(t[1],t[2]); ce(t[3],t[4]); ce(t[5],t[6]);
}
static __device__ inline void merge9(float t[K_NEI], const float o[K_NEI]) {
    float m[K_NEI];
#pragma unroll
    for (int i = 0; i < K_NEI; ++i) m[i] = fminf(t[i], o[K_NEI - 1 - i]);
    sort9(m);
#pragma unroll
    for (int i = 0; i < K_NEI; ++i) t[i] = m[i];
}
// pool the 4 partner lanes (lane ^16, ^32). Valid only for element-disjoint
// lists (true: each bank row is scanned by exactly one lane).
static __device__ inline void quad_merge(float t[K_NEI]) {
    float o[K_NEI];
#pragma unroll
    for (int i = 0; i < K_NEI; ++i) o[i] = __shfl_xor(t[i], 16, 64);
    merge9(t, o);
#pragma unroll
    for (int i = 0; i < K_NEI; ++i) o[i] = __shfl_xor(t[i], 32, 64);
    merge9(t, o);
}

// ---------------------------------------------------------------------------
// Kernel 1 (prep, round-5 rewrite): fp32 -> bf16 + row norms + init.
// Wave = 4 rows; lane: row = w*4 + l4, 32 B float4x2 load at col l15*8;
// 4-level 16-lane reduce; 16 B packed bf16 store. (Old version: 0.9 TB/s,
// latency-bound on 5-level reduce + 8 B stores.)
// ---------------------------------------------------------------------------
static __device__ inline unsigned pack2bf(float a, float b) {
    __hip_bfloat16 x = __float2bfloat16(a), y = __float2bfloat16(b);
    unsigned short ux = *(unsigned short*)&x, uy = *(unsigned short*)&y;
    return (unsigned)ux | ((unsigned)uy << 16);
}

__global__ void prep_kernel(const float* __restrict__ bank,
                            const float* __restrict__ feats,
                            __hip_bfloat16* __restrict__ bankbf,
                            __hip_bfloat16* __restrict__ featbf,
                            float* __restrict__ bsqn,
                            float* __restrict__ qsq,
                            int* __restrict__ thr_g,
                            int* __restrict__ done) {
    int w    = (blockIdx.x * blockDim.x + threadIdx.x) >> 6;
    int lane = threadIdx.x & 63;
    int l15  = lane & 15, l4 = lane >> 4;
    int row  = w * 4 + l4;
    if (row >= N + M) return;

    const float* src = (row < N) ? (bank + (size_t)row * D)
                                 : (feats + (size_t)(row - N) * D);
    const float4* s4 = (const float4*)src;
    float4 a = s4[l15 * 2], b = s4[l15 * 2 + 1];
    float s = a.x * a.x + a.y * a.y + a.z * a.z + a.w * a.w +
              b.x * b.x + b.y * b.y + b.z * b.z + b.w * b.w;
    // reduce over the 16 lanes of this row (xor 1,2,4,8 stays in-group)
#pragma unroll
    for (int off = 1; off < 16; off <<= 1) s += __shfl_xor(s, off, 64);

    __hip_bfloat16* dst = (row < N) ? (bankbf + (size_t)row * D)
                                    : (featbf + (size_t)(row - N) * D);
    uint4 p;
    p.x = pack2bf(a.x, a.y); p.y = pack2bf(a.z, a.w);
    p.z = pack2bf(b.x, b.y); p.w = pack2bf(b.z, b.w);
    ((uint4*)dst)[l15] = p;

    if (l15 == 0) {
        if (row < N) {
            bsqn[row] = -0.5f * s;
        } else {
            qsq[row - N] = s;
            thr_g[row - N] = 0x7f7f7f7f;   // 3.39e38f
        }
    }
    if (l15 == 1 && row >= N && (row - N) < QGROUPS) done[row - N] = 0;
}

// ---------------------------------------------------------------------------
// Kernel 2 (ROUND-5: two-pass with PER-QUERY tile keys).
//
// r4 failure (measured): tile keys pooled over the tile's 16 queries and
// compared against wave_max(g) — a single VALUE threshold across queries
// whose norms differ by ~2 sigma of the d2 tail — fired ~100% (MfmaUtil x
// dur = 2.07 full GEMMs). Fix: keys are per (tile, query).
//
// PASS 1 (branchless): full scan; per (rt,qt) tile, per lane: reg-max over
// the lane's 4 rows of (2*acc - qs) then quad-max over l4 (2 shfl) =
// -(min d2 over the tile's 16 rows) FOR QUERY l15. Stored bf16-TRUNCATED
// (negative values truncate toward +inf => stored >= true => safe) in
// wave-private LDS [4][64][2][4][16] (64 KB).
//
// BOUND: per query, 9th smallest of its 128 stored tile-minima (9 distinct
// tiles => 9 distinct rows => valid upper bound on the true 9th). Published
// cross-block via thr_g atomicMin, pooled cross-wave via sm_g.
//
// PASS 2 (sparse): per chunk, per lane: fire_q = (tk >= -g[q]*GUARD); tile
// executes iff ballot != 0. Exact: if row r is in query q's true top-9 then
// d2(r,q) <= true9th <= g_ownlane, so tk >= -d2 >= -g > -g*GUARD => the
// owning lane fires the tile, and the per-value test (acc >= h, d2 <= g)
// inserts it exactly as in r0-r3. Flags are evaluated fresh each chunk with
// the current (monotone-tightening) g; prefetched one chunk ahead with the
// then-current g (staler = looser = safe).
// ---------------------------------------------------------------------------
__global__ __launch_bounds__(256, 2)
void knn_main(const __hip_bfloat16* __restrict__ bankbf,
              const __hip_bfloat16* __restrict__ featbf,
              const float* __restrict__ bsqn,
              const float* __restrict__ qsqp,
              int* __restrict__ thr_g,
              float* __restrict__ part,
              int* __restrict__ done,
              float* __restrict__ out) {
    __shared__ unsigned short tk_lds[4][CHUNKS][RT][QT][16];   // 64 KB
    __shared__ __align__(16) float sm_g[4][QB];                // 1 KB
    __shared__ __align__(16) float sm_pool[4][QB][K_NEI];      // 9 KB
    __shared__ int sm_last;

    const int tid  = threadIdx.x;
    const int lane = tid & 63;
    const int wv   = tid >> 6;
    const int l15  = lane & 15, l4 = lane >> 4;

    const int seg   = blockIdx.x & 7;     // == XCD id (L2-resident segment)
    const int bq    = blockIdx.x >> 3;    // 0..63
    const int qbase = bq * QB;
    const int sbase = seg * SEG_LEN;

    // query fragments (B operand) in registers for the whole kernel
    bf16x8 qf[QT][4];
    float qs[QT];
#pragma unroll
    for (int qt = 0; qt < QT; ++qt) {
        int q = qbase + qt * 16 + l15;
        qs[qt] = qsqp[q];
#pragma unroll
        for (int ks = 0; ks < 4; ++ks)
            qf[qt][ks] = *(const bf16x8*)(featbf + (size_t)q * D + ks * 32 + l4 * 8);
    }

    // per-wave bank bases: row = sbase + wv*32 + rt*16 + l15, k-slice l4*8
    const __hip_bfloat16* ab[RT];
#pragma unroll
    for (int rt = 0; rt < RT; ++rt)
        ab[rt] = bankbf + (size_t)(sbase + wv * 32 + rt * 16 + l15) * D + l4 * 8;
    const float* ibq = bsqn + sbase + wv * 32 + l4 * 4;   // + rt*16 + ch*BB

    bf16x8 af[RT][4];
    floatx4 ini[RT];
#pragma unroll
    for (int rt = 0; rt < RT; ++rt) {
#pragma unroll
        for (int ks = 0; ks < 4; ++ks)
            af[rt][ks] = *(const bf16x8*)(ab[rt] + ks * 32);
        ini[rt] = *(const floatx4*)(ibq + rt * 16);
    }

    // ======================= PASS 1: branchless scan =======================
#pragma unroll 1
    for (int ci = 0; ci < CHUNKS; ++ci) {
        floatx4 acc[RT][QT];
#pragma unroll
        for (int rt = 0; rt < RT; ++rt)
#pragma unroll
            for (int qt = 0; qt < QT; ++qt)
                acc[rt][qt] = mfma16(af[rt][0], qf[qt][0], ini[rt]);
#pragma unroll
        for (int ks = 1; ks < 4; ++ks)
#pragma unroll
            for (int rt = 0; rt < RT; ++rt)
#pragma unroll
                for (int qt = 0; qt < QT; ++qt)
                    acc[rt][qt] = mfma16(af[rt][ks], qf[qt][ks], acc[rt][qt]);

        if (ci + 1 < CHUNKS) {
            const size_t coff = (size_t)(ci + 1) * (BB * D);
#pragma unroll
            for (int rt = 0; rt < RT; ++rt) {
#pragma unroll
                for (int ks = 0; ks < 4; ++ks)
                    af[rt][ks] = *(const bf16x8*)(ab[rt] + coff + ks * 32);
                ini[rt] = *(const floatx4*)(ibq + (ci + 1) * BB + rt * 16);
            }
        }

        // per-query tile keys: k = -(min d2 over the tile's 16 rows) for
        // query l15; bf16-truncate (negative -> rounds up -> safe)
#pragma unroll
        for (int rt = 0; rt < RT; ++rt) {
#pragma unroll
            for (int qt = 0; qt < QT; ++qt) {
                float m = fmaxf(fmaxf(acc[rt][qt][0], acc[rt][qt][1]),
                                fmaxf(acc[rt][qt][2], acc[rt][qt][3]));
                float k = fmaf(2.f, m, -qs[qt]);
                k = fmaxf(k, __shfl_xor(k, 16, 64));
                k = fmaxf(k, __shfl_xor(k, 32, 64));
                if (l4 == 0)
                    tk_lds[wv][ci][rt][qt][l15] =
                        (unsigned short)(__float_as_uint(k) >> 16);
            }
        }
    }

    // ---- bound: per query, 9th smallest of its 128 tile-minima ------------
    float g[QT];
#pragma unroll
    for (int qt = 0; qt < QT; ++qt) {
        float tb[K_NEI];
#pragma unroll
        for (int j = 0; j < K_NEI; ++j) tb[j] = FLT_MAX;
#pragma unroll 1
        for (int ci = 0; ci < CHUNKS; ++ci) {
#pragma unroll
            for (int rt = 0; rt < RT; ++rt) {
                float tk = __uint_as_float(
                    ((unsigned)tk_lds[wv][ci][rt][qt][l15]) << 16);
                float d2 = fmaxf(-tk, 0.f);
                if (d2 < tb[K_NEI - 1]) {
                    tb[K_NEI - 1] = d2;
#pragma unroll
                    for (int s = K_NEI - 1; s > 0; --s) ce(tb[s - 1], tb[s]);
                }
            }
        }
        g[qt] = tb[K_NEI - 1];
        if (l4 == 0)
            atomicMin(&thr_g[qbase + qt * 16 + l15], __float_as_int(g[qt]));
        sm_g[wv][qt * 16 + l15] = g[qt];
    }
    __syncthreads();
    // cross-wave pool + cross-block bounds
#pragma unroll
    for (int qt = 0; qt < QT; ++qt) {
        float m0 = fminf(fminf(sm_g[0][qt * 16 + l15], sm_g[1][qt * 16 + l15]),
                         fminf(sm_g[2][qt * 16 + l15], sm_g[3][qt * 16 + l15]));
        g[qt] = fminf(g[qt], m0);
        int tg = __hip_atomic_load(&thr_g[qbase + qt * 16 + l15],
                                   __ATOMIC_RELAXED, __HIP_MEMORY_SCOPE_AGENT);
        g[qt] = fminf(g[qt], __int_as_float(tg));
    }

    float t9[QT][K_NEI];
#pragma unroll
    for (int qt = 0; qt < QT; ++qt)
#pragma unroll
        for (int j = 0; j < K_NEI; ++j) t9[qt][j] = FLT_MAX;

    // ======================= PASS 2: sparse exact pass =====================
    float thr[QT], h[QT];
    int tgl[QT];
#pragma unroll
    for (int qt = 0; qt < QT; ++qt) tgl[qt] = 0x7f7f7f7f;

    unsigned long long bw[RT][QT];
    int rtf[RT];
    // prologue flags + loads for chunk 0
#pragma unroll
    for (int qt = 0; qt < QT; ++qt) thr[qt] = -g[qt] * GUARD;
#pragma unroll
    for (int rt = 0; rt < RT; ++rt) {
        rtf[rt] = 0;
#pragma unroll
        for (int qt = 0; qt < QT; ++qt) {
            float tk = __uint_as_float(
                ((unsigned)tk_lds[wv][0][rt][qt][l15]) << 16);
            bw[rt][qt] = __ballot(tk >= thr[qt]);
            rtf[rt] |= (bw[rt][qt] != 0);
        }
    }
#pragma unroll
    for (int rt = 0; rt < RT; ++rt) {
        if (rtf[rt]) {
#pragma unroll
            for (int ks = 0; ks < 4; ++ks)
                af[rt][ks] = *(const bf16x8*)(ab[rt] + ks * 32);
        }
        ini[rt] = *(const floatx4*)(ibq + rt * 16);
    }

#pragma unroll 1
    for (int ci = 0; ci < CHUNKS; ++ci) {
        // gates for this chunk (g tightens monotonically)
#pragma unroll
        for (int qt = 0; qt < QT; ++qt) {
            thr[qt] = -g[qt] * GUARD;
            h[qt]   = 0.5f * (qs[qt] - g[qt] * GUARD);
        }

        // MFMA only on fired tiles
        floatx4 acc[RT][QT];
#pragma unroll
        for (int rt = 0; rt < RT; ++rt) {
            if (rtf[rt]) {
#pragma unroll
                for (int qt = 0; qt < QT; ++qt) {
                    if (bw[rt][qt]) {
                        floatx4 a = mfma16(af[rt][0], qf[qt][0], ini[rt]);
                        a = mfma16(af[rt][1], qf[qt][1], a);
                        a = mfma16(af[rt][2], qf[qt][2], a);
                        a = mfma16(af[rt][3], qf[qt][3], a);
                        acc[rt][qt] = a;
                    }
                }
            }
        }

        // prefetch next chunk's flags (current g: looser-or-equal => safe)
        // and issue its fragment loads early
        unsigned long long nbw[RT][QT];
        int nrtf[RT];
        if (ci + 1 < CHUNKS) {
#pragma unroll
            for (int rt = 0; rt < RT; ++rt) {
                nrtf[rt] = 0;
#pragma unroll
                for (int qt = 0; qt < QT; ++qt) {
                    float tk = __uint_as_float(
                        ((unsigned)tk_lds[wv][ci + 1][rt][qt][l15]) << 16);
                    nbw[rt][qt] = __ballot(tk >= thr[qt]);
                    nrtf[rt] |= (nbw[rt][qt] != 0);
                }
            }
            const size_t coff = (size_t)(ci + 1) * (BB * D);
#pragma unroll
            for (int rt = 0; rt < RT; ++rt) {
                if (nrtf[rt]) {
#pragma unroll
                    for (int ks = 0; ks < 4; ++ks)
                        af[rt][ks] = *(const bf16x8*)(ab[rt] + coff + ks * 32);
                }
                ini[rt] = *(const floatx4*)(ibq + (ci + 1) * BB + rt * 16);
            }
        }

        // selection on fired tiles
#pragma unroll
        for (int rt = 0; rt < RT; ++rt) {
            if (rtf[rt]) {
#pragma unroll
                for (int qt = 0; qt < QT; ++qt) {
                    if (bw[rt][qt]) {
                        float a0 = acc[rt][qt][0], a1 = acc[rt][qt][1];
                        float a2 = acc[rt][qt][2], a3 = acc[rt][qt][3];
                        float mx = fmaxf(fmaxf(a0, a1), fmaxf(a2, a3));
                        if (__ballot(mx >= h[qt])) {
#pragma unroll
                            for (int r = 0; r < 4; ++r) {
                                float a = acc[rt][qt][r];
                                if (a >= h[qt]) {
                                    float d2 = fmaxf(fmaf(-2.f, a, qs[qt]), 0.f);
                                    if (d2 <= g[qt]) {
                                        t9[qt][K_NEI - 1] = d2;
#pragma unroll
                                        for (int s = K_NEI - 1; s > 0; --s)
                                            ce(t9[qt][s - 1], t9[qt][s]);
                                        g[qt] = fminf(g[qt], t9[qt][K_NEI - 1]);
                                    }
                                }
                            }
                        }
                    }
                }
            }
        }
#pragma unroll
        for (int rt = 0; rt < RT; ++rt) {
            rtf[rt] = nrtf[rt];
#pragma unroll
            for (int qt = 0; qt < QT; ++qt) bw[rt][qt] = nbw[rt][qt];
        }

        // periodic cross-block gate refresh (stale = looser = safe)
        if ((ci & 7) == 0) {
#pragma unroll
            for (int qt = 0; qt < QT; ++qt)
                tgl[qt] = __hip_atomic_load(&thr_g[qbase + qt * 16 + l15],
                                            __ATOMIC_RELAXED,
                                            __HIP_MEMORY_SCOPE_AGENT);
        } else if ((ci & 7) == 2) {
#pragma unroll
            for (int qt = 0; qt < QT; ++qt)
                g[qt] = fminf(g[qt], __int_as_float(tgl[qt]));
        }
    }

    // ---- epilogue: quad pool (disjoint), then 4-wave pool via LDS ---------
#pragma unroll
    for (int qt = 0; qt < QT; ++qt) quad_merge(t9[qt]);
    if (l4 == 0) {
#pragma unroll
        for (int qt = 0; qt < QT; ++qt)
#pragma unroll
            for (int j = 0; j < K_NEI; ++j)
                sm_pool[wv][qt * 16 + l15][j] = t9[qt][j];
    }
    __syncthreads();
    if (tid < QB) {
        float R[K_NEI];
#pragma unroll
        for (int j = 0; j < K_NEI; ++j) R[j] = sm_pool[0][tid][j];
#pragma unroll
        for (int w = 1; w < 4; ++w) {
            float o[K_NEI];
#pragma unroll
            for (int j = 0; j < K_NEI; ++j) o[j] = sm_pool[w][tid][j];
            merge9(R, o);
        }
        float* dst = part + ((size_t)(qbase + tid) * SEGS + seg) * K_NEI;
#pragma unroll
        for (int j = 0; j < K_NEI; ++j) dst[j] = R[j];
    }

    // ---- fused final: last seg-block of this qgroup folds 8 sorted lists --
    __threadfence();
    __syncthreads();
    if (tid == 0)
        sm_last = (atomicAdd(&done[bq], 1) == SEGS - 1) ? 1 : 0;
    __syncthreads();
    if (sm_last && tid < QB) {
        int q = qbase + tid;
        const float* p = part + (size_t)q * SEGS * K_NEI;
        float R[K_NEI], nx[K_NEI];
#pragma unroll
        for (int j = 0; j < K_NEI; ++j)
            R[j] = __hip_atomic_load(p + j, __ATOMIC_RELAXED,
                                     __HIP_MEMORY_SCOPE_AGENT);
#pragma unroll
        for (int j = 0; j < K_NEI; ++j)
            nx[j] = __hip_atomic_load(p + K_NEI + j, __ATOMIC_RELAXED,
                                      __HIP_MEMORY_SCOPE_AGENT);
#pragma unroll 1
        for (int s = 1; s < SEGS; ++s) {
            float o[K_NEI];
#pragma unroll
            for (int j = 0; j < K_NEI; ++j) o[j] = nx[j];
            if (s + 1 < SEGS) {
#pragma unroll
                for (int j = 0; j < K_NEI; ++j)
                    nx[j] = __hip_atomic_load(p + (s + 1) * K_NEI + j,
                                              __ATOMIC_RELAXED,
                                              __HIP_MEMORY_SCOPE_AGENT);
            }
            merge9(R, o);
        }
        float sum = 0.f;
#pragma unroll
        for (int j = 0; j < K_NEI; ++j) sum += sqrtf(fmaxf(R[j], 0.f));
        out[q] = sum * (1.0f / 9.0f);
    }
}

// ---------------------------------------------------------------------------
extern "C" void kernel_launch(void* const* d_in, const int* in_sizes, int n_in,
                              void* d_out, int out_size, void* d_ws, size_t ws_size,
                              hipStream_t stream) {
    const float* feats = (const float*)d_in[0];   // [M, D]
    const float* bank  = (const float*)d_in[1];   // [N, D]

    char* w = (char*)d_ws;
    __hip_bfloat16* bankbf = (__hip_bfloat16*)w;                       // 16 MB
    __hip_bfloat16* featbf = (__hip_bfloat16*)(w + (size_t)N * D * 2); // 1 MB
    float* bsqn = (float*)(w + (size_t)(N + M) * D * 2);               // 256 KB
    float* qsqp = bsqn + N;                                            // 16 KB
    float* part = qsqp + M;                                            // 1.2 MB
    int*   thr_g = (int*)(part + (size_t)M * SEGS * K_NEI);            // 16 KB
    int*   done  = thr_g + M;                                          // 256 B
    float* out  = (float*)d_out;

    prep_kernel<<<(N + M) / 16, 256, 0, stream>>>(bank, feats, bankbf, featbf,
                                                  bsqn, qsqp, thr_g, done);
    knn_main<<<QGROUPS * SEGS, 256, 0, stream>>>(bankbf, featbf, bsqn, qsqp,
                                                 thr_g, part, done, out);
}